// Round 5
// baseline (1505.321 us; speedup 1.0000x reference)
//
#include <hip/hip_runtime.h>
#include <stdint.h>

#define NSITES 256
#define NHID   64
#define BATCH  8192

// ---------------- threefry2x32 (exact JAX semantics) ----------------
__device__ __forceinline__ uint32_t rotl32(uint32_t v, int d) {
  return (v << d) | (v >> (32 - d));
}

__device__ __forceinline__ void tf2x32(uint32_t k0, uint32_t k1,
                                       uint32_t x0, uint32_t x1,
                                       uint32_t& o0, uint32_t& o1) {
  uint32_t ks2 = k0 ^ k1 ^ 0x1BD11BDAu;
  x0 += k0; x1 += k1;
#define TFR4(a,b,c,d) \
  x0 += x1; x1 = rotl32(x1,a); x1 ^= x0; \
  x0 += x1; x1 = rotl32(x1,b); x1 ^= x0; \
  x0 += x1; x1 = rotl32(x1,c); x1 ^= x0; \
  x0 += x1; x1 = rotl32(x1,d); x1 ^= x0;
  TFR4(13,15,26,6)   x0 += k1;  x1 += ks2 + 1u;
  TFR4(17,29,16,24)  x0 += ks2; x1 += k0  + 2u;
  TFR4(13,15,26,6)   x0 += k0;  x1 += k1  + 3u;
  TFR4(17,29,16,24)  x0 += k1;  x1 += ks2 + 4u;
  TFR4(13,15,26,6)   x0 += ks2; x1 += k0  + 5u;
#undef TFR4
  o0 = x0; o1 = x1;
}

__device__ __forceinline__ float gumb_from_bits(uint32_t bits) {
  float f = __uint_as_float((bits >> 9) | 0x3f800000u) - 1.0f;
  float u = (f == 0.0f) ? 1.17549435e-38f : f;
  return -logf(-logf(u));
}

__device__ __forceinline__ uint32_t rbits32(uint32_t k0, uint32_t k1, uint32_t e) {
  uint32_t a, b;
  tf2x32(k0, k1, 0u, e, a, b);
  return a ^ b;
}

// ---------------- gumbel precompute kernel ----------------
__global__ void gumbel_precompute(float2* __restrict__ g) {
  int idx = blockIdx.x * blockDim.x + threadIdx.x;
  if (idx >= NSITES * BATCH) return;
  int t = idx >> 13;
  int b = idx & (BATCH - 1);
  uint32_t kt0, kt1;
  tf2x32(0u, 1234u, 0u, (uint32_t)t, kt0, kt1);
  uint32_t r0 = rbits32(kt0, kt1, (uint32_t)(2 * b));
  uint32_t r1 = rbits32(kt0, kt1, (uint32_t)(2 * b + 1));
  g[idx] = make_float2(gumb_from_bits(r0), gumb_from_bits(r1));
}

// XLA's logistic_expander form: 0.5 + 0.5*tanh(0.5*x)
__device__ __forceinline__ float sigmoid_xla(float x) {
  return 0.5f + 0.5f * tanhf(0.5f * x);
}

// ================= one sample per wave, weights VGPR-resident =============
// Two mechanisms force the 192 per-lane Wh values to stay in VGPRs:
// 1) 20 KiB dummy LDS per 64-thread block -> hardware occupancy ceiling of
//    8 blocks/CU = 2 waves/EU -> the register allocator's budget is 256
//    VGPRs and rematerializing for higher occupancy is pointless (the
//    backend derives its occupancy target from LDS, deterministically).
// 2) volatile weight loads -> execution count is fixed by the language, so
//    the allocator CANNOT legally rematerialize them inside the t-loop; with
//    a 256-reg budget and ~226 live values, registers are its best option.
template <bool PRE>
__global__ __launch_bounds__(64) __attribute__((amdgpu_waves_per_eu(2, 2)))
void rnn_v1(const float* __restrict__ Wi, const float* __restrict__ Wh,
            const float* __restrict__ bb, const float* __restrict__ Wd,
            const float* __restrict__ bd, const float2* __restrict__ g,
            float* __restrict__ out_s, float* __restrict__ out_lp) {
  __shared__ float occ_clamp[5120];          // 20 KiB -> 8 blocks/CU max
  const int lane = threadIdx.x;
  const int b = blockIdx.x;
  ((volatile float*)occ_clamp)[lane] = 0.0f; // keep the LDS allocation live

  // ---- load per-lane weights (volatile: non-rematerializable) ----
  const volatile float* Whv = Wh;
  const volatile float* Wiv = Wi;
  const volatile float* bbv = bb;
  const volatile float* Wdv = Wd;

  float wz[NHID], wr[NHID], wh[NHID];
#pragma unroll
  for (int j = 0; j < NHID; ++j) {
    wz[j] = Whv[j * 192 + lane];
    wr[j] = Whv[j * 192 + 64 + lane];
    wh[j] = Whv[j * 192 + 128 + lane];
  }
  const float b1z = bbv[192 + lane];
  const float b1r = bbv[192 + 64 + lane];
  const float b1h = bbv[192 + 128 + lane];
  const float m0z = bbv[lane], m0r = bbv[64 + lane], m0h = bbv[128 + lane];
  float m1z = Wiv[lane] + m0z, m1r = Wiv[64 + lane] + m0r, m1h = Wiv[128 + lane] + m0h;
  float m2z = Wiv[192 + lane] + m0z, m2r = Wiv[192 + 64 + lane] + m0r,
        m2h = Wiv[192 + 128 + lane] + m0h;
  float wd0 = Wdv[lane * 2 + 0], wd1 = Wdv[lane * 2 + 1];
  const float bd0 = bd[0], bd1 = bd[1];

  // pins AFTER all loads (separate loop so the load burst pipelines)
#pragma unroll
  for (int j = 0; j < NHID; ++j)
    asm volatile("" : "+v"(wz[j]), "+v"(wr[j]), "+v"(wh[j]));
  asm volatile("" : "+v"(m1z), "+v"(m1r), "+v"(m1h), "+v"(m2z), "+v"(m2r));
  asm volatile("" : "+v"(m2h), "+v"(wd0), "+v"(wd1));

  float h = 0.0f, lpsum = 0.0f;
  float xz = m0z, xr = m0r, xh = m0h;   // t=0: zero one-hot input

  for (int t = 0; t < NSITES; ++t) {
    float g0, g1;
    if (PRE) {
      const float2 gc = g[t * BATCH + b];
      g0 = gc.x; g1 = gc.y;
    } else {
      uint32_t kt0, kt1;
      tf2x32(0u, 1234u, 0u, (uint32_t)t, kt0, kt1);
      g0 = gumb_from_bits(rbits32(kt0, kt1, (uint32_t)(2 * b)));
      g1 = gumb_from_bits(rbits32(kt0, kt1, (uint32_t)(2 * b + 1)));
    }

    float az = 0.0f, ar = 0.0f, ah = 0.0f;
#pragma unroll
    for (int j = 0; j < NHID; ++j) {
      const float hj = __int_as_float(__builtin_amdgcn_readlane(__float_as_int(h), j));
      az = fmaf(hj, wz[j], az);
      ar = fmaf(hj, wr[j], ar);
      ah = fmaf(hj, wh[j], ah);
    }
    const float rz = az + b1z;
    const float rr = ar + b1r;
    const float rh = ah + b1h;

    const float zg = sigmoid_xla(xz + rz);
    const float rg = sigmoid_xla(xr + rr);
    const float hg = tanhf(xh + rg * rh);
    h = zg * h + (1.0f - zg) * hg;

    float p0 = h * wd0, p1 = h * wd1;
#pragma unroll
    for (int off = 32; off > 0; off >>= 1) {
      p0 += __shfl_xor(p0, off, 64);
      p1 += __shfl_xor(p1, off, 64);
    }
    const float l0 = p0 + bd0, l1 = p1 + bd1;

    const float mmax = fmaxf(l0, l1);
    const float sh0 = l0 - mmax, sh1 = l1 - mmax;
    const float lse = logf(expf(sh0) + expf(sh1));

    const int s = ((l1 + g1) > (l0 + g0)) ? 1 : 0;

    lpsum += (s ? sh1 : sh0) - lse;
    if (lane == 0) out_s[(size_t)b * NSITES + t] = (float)s;
    xz = s ? m2z : m1z;
    xr = s ? m2r : m1r;
    xh = s ? m2h : m1h;
  }

  if (lane == 0) out_lp[b] = 0.5f * lpsum;
}

extern "C" void kernel_launch(void* const* d_in, const int* in_sizes, int n_in,
                              void* d_out, int out_size, void* d_ws, size_t ws_size,
                              hipStream_t stream) {
  const float* Wi = (const float*)d_in[1];
  const float* Wh = (const float*)d_in[2];
  const float* bb = (const float*)d_in[3];
  const float* Wd = (const float*)d_in[4];
  const float* bd = (const float*)d_in[5];

  float* out    = (float*)d_out;
  float* out_s  = out;                           // [8192][256]
  float* out_lp = out + (size_t)BATCH * NSITES;  // [8192]

  const size_t gbytes = (size_t)NSITES * BATCH * sizeof(float2);
  if (ws_size >= gbytes) {
    float2* g = (float2*)d_ws;
    gumbel_precompute<<<(NSITES * BATCH) / 256, 256, 0, stream>>>(g);
    rnn_v1<true><<<BATCH, 64, 0, stream>>>(Wi, Wh, bb, Wd, bd, g, out_s, out_lp);
  } else {
    rnn_v1<false><<<BATCH, 64, 0, stream>>>(Wi, Wh, bb, Wd, bd, nullptr, out_s, out_lp);
  }
}